// Round 7
// baseline (274.060 us; speedup 1.0000x reference)
//
#include <hip/hip_runtime.h>
#include <hip/hip_bf16.h>
#include <math.h>

#define N_TOK 8192
#define DIM   1024
#define NEXP  16
#define TOPK  2
#define CAPE  1024
#define NSLOT (N_TOK*TOPK)

typedef __attribute__((ext_vector_type(8))) short     short8;
typedef __attribute__((ext_vector_type(4))) float     floatx4;
typedef __attribute__((ext_vector_type(4))) unsigned short ushort4v;

__device__ __forceinline__ unsigned short f2bf(float f) {
    unsigned u = __float_as_uint(f);
    u += 0x7FFFu + ((u >> 16) & 1u);   // round-to-nearest-even
    return (unsigned short)(u >> 16);
}

// async global->LDS, 16B per lane; LDS dest = wave-uniform base + lane*16
#define GLOAD_LDS16(g, l) __builtin_amdgcn_global_load_lds( \
    (const __attribute__((address_space(1))) unsigned int*)(g), \
    (__attribute__((address_space(3))) unsigned int*)(l), 16, 0, 0)

#define RAW_BARRIER() asm volatile("s_barrier" ::: "memory")

// --- fused: weight fp32->bf16 cvt + gw transpose + counter zeroing --------
__global__ void cvt_gwt_zero_kernel(const float* __restrict__ ew,
                                    unsigned short* __restrict__ Wb,
                                    const float* __restrict__ gw,
                                    float* __restrict__ gwT,
                                    int* __restrict__ zws) {
    const int i = blockIdx.x * 256 + threadIdx.x;
    if (blockIdx.x == 0 && threadIdx.x < 64) zws[threadIdx.x] = 0;
    if (i < DIM * NEXP) {
        int d = i >> 4, e = i & 15;
        gwT[e * DIM + d] = gw[i];
    }
    floatx4 v = ((const floatx4*)ew)[i];
    ushort4v o;
    o[0] = f2bf(v[0]); o[1] = f2bf(v[1]); o[2] = f2bf(v[2]); o[3] = f2bf(v[3]);
    ((ushort4v*)Wb)[i] = o;
}

// ------- gate: 16 tokens per block, one (token,expert) pair per thread -----
// Round-7 restructure (old: 1 token/wave, 64KB gwT walk per wave thrashing
// L1 + 96-shuffle reduce -> 50 us latency-bound). New:
//   P1: block streams 16 x rows coalesced; emits Xb bf16; stages fp32 x in
//       LDS with c^(t&3) float4-swizzle (phase-2 conflict-free).
//   P2: thread (t,e) owns the FULL 1024-length fp32 dot (x from LDS with
//       16-way broadcast, gwT row from L1/L2). No cross-lane reduction.
//   P3: per-token top-2 scan (same strict-> tie semantics) + fused bucket
//       histogram (32 slots/block); bucket pos stashed in slot_bpos.
__global__ __launch_bounds__(256) void gate_kernel(
        const float* __restrict__ x,
        const float* __restrict__ gwT,
        const float* __restrict__ gb,
        int* __restrict__ slot_expert,
        unsigned long long* __restrict__ slot_key,
        float* __restrict__ slot_gate,
        unsigned short* __restrict__ Xb,
        int* __restrict__ counts,
        unsigned long long* __restrict__ buckets,
        int* __restrict__ slot_bpos) {   // == slot_keep array (temp use)
    __shared__ float xs[16][1024];       // 64 KB, float4-swizzled
    __shared__ float lg[16][17];         // logits, padded
    __shared__ int se[32];
    __shared__ unsigned long long sk[32];
    __shared__ int lcnt[NEXP], lbase[NEXP], lpo[32];
    const int tid = threadIdx.x;
    const int t0  = blockIdx.x * 16;
    if (tid < NEXP) lcnt[tid] = 0;

    // --- phase 1: load + cvt + stage ---
    const floatx4* xg = (const floatx4*)(x + (size_t)t0 * DIM);
    ushort4v* xb4 = (ushort4v*)Xb + (size_t)t0 * 256;
#pragma unroll 4
    for (int j = 0; j < 16; j++) {
        int idx = tid + j * 256;          // float4 index in the 16-row tile
        int tt = idx >> 8, c = idx & 255;
        floatx4 v = xg[idx];
        ushort4v o;
        o[0] = f2bf(v[0]); o[1] = f2bf(v[1]); o[2] = f2bf(v[2]); o[3] = f2bf(v[3]);
        xb4[idx] = o;
        *(floatx4*)&xs[tt][(c ^ (tt & 3)) * 4] = v;
    }
    __syncthreads();

    // --- phase 2: full dot per thread ---
    {
        const int tl = tid >> 4, e = tid & 15;
        const floatx4* wr = (const floatx4*)(gwT + (size_t)e * DIM);
        const int tswz = tl & 3;
        floatx4 acc = {0.f, 0.f, 0.f, 0.f};
#pragma unroll 8
        for (int c = 0; c < 256; c++) {
            floatx4 xv = *(const floatx4*)&xs[tl][(c ^ tswz) * 4];
            floatx4 wv = wr[c];
            acc[0] += xv[0] * wv[0];
            acc[1] += xv[1] * wv[1];
            acc[2] += xv[2] * wv[2];
            acc[3] += xv[3] * wv[3];
        }
        lg[tl][e] = (acc[0] + acc[1]) + (acc[2] + acc[3]) + gb[e];
    }
    __syncthreads();

    // --- phase 3: top-2 + softmax + records ---
    if (tid < 16) {
        const int t = t0 + tid;
        float v0 = -1e30f; int i0 = 0;
#pragma unroll
        for (int e = 0; e < NEXP; e++) {
            float v = lg[tid][e];
            if (v > v0) { v0 = v; i0 = e; }   // strict > : lowest index on tie
        }
        float v1 = -1e30f; int i1 = 0;
#pragma unroll
        for (int e = 0; e < NEXP; e++) {
            float v = lg[tid][e];
            if (e != i0 && v > v1) { v1 = v; i1 = e; }
        }
        float e1 = expf(v1 - v0);
        float den = 1.f + e1;
        float g0 = 1.f / den;       // max gate score (>= 0.5)
        float g1 = e1 / den;
        unsigned sb = __float_as_uint(g0);  // g0 > 0 -> bit order == float order
        int s0 = 2 * t, s1 = 2 * t + 1;
        slot_expert[s0] = i0; slot_expert[s1] = i1;
        slot_gate[s0]   = g0; slot_gate[s1]   = g1;
        unsigned long long hi = ((unsigned long long)sb) << 32;
        unsigned long long k0 = hi | (unsigned)(0xFFFFFFFFu - (unsigned)s0);
        unsigned long long k1 = hi | (unsigned)(0xFFFFFFFFu - (unsigned)s1);
        slot_key[s0] = k0; slot_key[s1] = k1;
        se[2 * tid] = i0; se[2 * tid + 1] = i1;
        sk[2 * tid] = k0; sk[2 * tid + 1] = k1;
    }
    __syncthreads();
    if (tid < 32) lpo[tid] = atomicAdd(&lcnt[se[tid]], 1);
    __syncthreads();
    if (tid < NEXP) lbase[tid] = lcnt[tid] ? atomicAdd(&counts[tid], lcnt[tid]) : 0;
    __syncthreads();
    if (tid < 32) {
        int e = se[tid];
        int p = lbase[e] + lpo[tid];
        buckets[(size_t)e * NSLOT + p] = sk[tid];
        slot_bpos[blockIdx.x * 32 + tid] = p;   // dense unique pos within expert
    }
}

// ---- keep+compact merged: one WAVE per slot, rank == elist position -------
__global__ __launch_bounds__(256) void keep_compact_kernel(
        const int* __restrict__ slot_expert,
        const unsigned long long* __restrict__ slot_key,
        const int* __restrict__ counts,
        const unsigned long long* __restrict__ buckets,
        int* __restrict__ slot_keep,     // in: bucket pos; out: keep flag
        int* __restrict__ elist,
        int* __restrict__ slot_pos) {
    const int wv   = threadIdx.x >> 6;
    const int lane = threadIdx.x & 63;
    const int s    = blockIdx.x * 4 + wv;
    const int e    = slot_expert[s];
    const int c    = counts[e];
    int kp = 1, pos;
    if (c <= CAPE) {
        pos = slot_keep[s];              // bucket insertion index
    } else {
        const unsigned long long k = slot_key[s];
        const unsigned long long* bk = buckets + (size_t)e * NSLOT;
        int rank = 0;
        for (int i = lane; i < c; i += 64) rank += (bk[i] > k) ? 1 : 0;
#pragma unroll
        for (int off = 32; off > 0; off >>= 1) rank += __shfl_down(rank, off, 64);
        rank = __shfl(rank, 0, 64);
        kp  = (rank < CAPE) ? 1 : 0;
        pos = rank;
    }
    if (lane == 0) {
        slot_keep[s] = kp;
        if (kp) {
            int p = e * CAPE + pos;
            elist[p]    = s;
            slot_pos[s] = p;
        }
    }
}

// ------- base (atomic-fallback path only): out[t] = (dropped g sum)*x[t] ---
__global__ void base_kernel(const float* __restrict__ x,
                            const int* __restrict__ keep,
                            const float* __restrict__ gate,
                            float* __restrict__ out) {
    int i = blockIdx.x * blockDim.x + threadIdx.x;   // float4 index
    int t = i >> 8;                                  // 256 float4 per row
    float c = 0.f;
    if (!keep[2 * t])     c += gate[2 * t];
    if (!keep[2 * t + 1]) c += gate[2 * t + 1];
    floatx4 v = ((const floatx4*)x)[i];
    ((floatx4*)out)[i] = v * c;
}

// --------- grouped expert GEMM: 256x128 tile, BK=32, 2 blocks/CU -----------
// Round-2 proven core, verbatim.
template <bool STORE_YS>
__global__ __launch_bounds__(512, 4)
void moe_gemm(const unsigned short* __restrict__ Xb,
              const unsigned short* __restrict__ Wb,
              const float* __restrict__ eb,
              const int* __restrict__ elist,
              const int* __restrict__ counts,
              const float* __restrict__ slot_gate,
              float* __restrict__ ys,
              float* __restrict__ out) {
    __shared__ unsigned short As[2][256 * 32];   // 16 KB x2
    __shared__ unsigned short Bs[2][128 * 32];   //  8 KB x2

    const int e  = blockIdx.z;
    int ne = counts[e]; if (ne > CAPE) ne = CAPE;
    const int m0 = blockIdx.y * 256;
    if (m0 >= ne) return;
    const int n0   = blockIdx.x * 128;
    const int tid  = threadIdx.x;
    const int wv   = tid >> 6;
    const int lane = tid & 63;
    const int q    = lane >> 4;
    const int l15  = lane & 15;
    const int wm   = (wv >> 1) * 64;   // wave M offset (4 M-waves)
    const int wn   = (wv & 1) * 64;    // wave N offset (2 N-waves)

    const int srow = wv * 16 + (lane >> 2);           // 0..127
    const int jsrc = (lane & 3) ^ ((lane >> 3) & 3);
    const unsigned short* gA0;
    const unsigned short* gA1;
    {
        int m = m0 + srow;
        int slot = elist[e * CAPE + (m < ne ? m : 0)];
        gA0 = Xb + (size_t)(slot >> 1) * DIM + jsrc * 8;
        m = m0 + 128 + srow;
        slot = elist[e * CAPE + (m < ne ? m : 0)];
        gA1 = Xb + (size_t)(slot >> 1) * DIM + jsrc * 8;
    }
    const unsigned short* gB0 =
        Wb + (size_t)e * DIM * DIM + (size_t)(n0 + srow) * DIM + jsrc * 8;

#define STAGE(b, k0) do { \
    GLOAD_LDS16(gA0 + (k0), &As[b][(wv * 16) * 32]); \
    GLOAD_LDS16(gA1 + (k0), &As[b][(128 + wv * 16) * 32]); \
    GLOAD_LDS16(gB0 + (k0), &Bs[b][(wv * 16) * 32]); } while (0)

    STAGE(0, 0);
    STAGE(1, 32);

    const int swz  = (q ^ ((l15 >> 1) & 3)) * 8;
    const int aoff = (wm + l15) * 32 + swz;
    const int boff = (wn + l15) * 32 + swz;

    floatx4 acc[4][4] = {};
    short8 a[4], b[4];

    for (int t = 0; t < 32; t++) {
        const int cur = t & 1;
        if (t == 31) { asm volatile("s_waitcnt vmcnt(0)" ::: "memory"); }
        else         { asm volatile("s_waitcnt vmcnt(3)" ::: "memory"); }
        __builtin_amdgcn_sched_barrier(0);
        RAW_BARRIER();                       // tile-t data visible to all

        const unsigned short* A_ = &As[cur][0];
        const unsigned short* B_ = &Bs[cur][0];
#pragma unroll
        for (int fi = 0; fi < 4; fi++) a[fi] = *(const short8*)(A_ + aoff + fi * 512);
#pragma unroll
        for (int fj = 0; fj < 4; fj++) b[fj] = *(const short8*)(B_ + boff + fj * 512);

        __builtin_amdgcn_s_setprio(1);
#pragma unroll
        for (int fi = 0; fi < 4; fi++)
#pragma unroll
            for (int fj = 0; fj < 4; fj++)
                acc[fi][fj] = __builtin_amdgcn_mfma_f32_16x16x32_bf16(
                    a[fi], b[fj], acc[fi][fj], 0, 0, 0);
        __builtin_amdgcn_s_setprio(0);
        RAW_BARRIER();                       // all reads of buf[cur] complete

        if (t + 2 < 32) STAGE(cur, (t + 2) * 32);   // overwrite buf[cur]
    }
#undef STAGE

    float ebv[4];
#pragma unroll
    for (int fj = 0; fj < 4; fj++)
        ebv[fj] = eb[e * DIM + n0 + wn + fj * 16 + l15];
#pragma unroll
    for (int fi = 0; fi < 4; fi++) {
        const int mrow = m0 + wm + fi * 16 + q * 4;
#pragma unroll
        for (int r = 0; r < 4; r++) {
            int m = mrow + r;
            if (m >= ne) continue;
            if (STORE_YS) {
                float* yrow = ys + ((size_t)e * CAPE + m) * DIM + n0 + wn;
#pragma unroll
                for (int fj = 0; fj < 4; fj++)
                    yrow[fj * 16 + l15] = acc[fi][fj][r] + ebv[fj];
            } else {
                int slot = elist[e * CAPE + m];
                int tok  = slot >> 1;
                float g  = slot_gate[slot];
                float* orow = out + (size_t)tok * DIM + n0 + wn;
#pragma unroll
                for (int fj = 0; fj < 4; fj++)
                    atomicAdd(orow + fj * 16 + l15, g * (acc[fi][fj][r] + ebv[fj]));
            }
        }
    }
}

// ---------------- combine: out = sum_k g_k * (keep ? ys[pos] : x) ----------
__global__ void combine_kernel(const float* __restrict__ x,
                               const float* __restrict__ ys,
                               const int* __restrict__ keep,
                               const int* __restrict__ pos,
                               const float* __restrict__ gate,
                               float* __restrict__ out) {
    int i = blockIdx.x * 256 + threadIdx.x;   // float4 index
    int t = i >> 8;
    int c = i & 255;
    int s0 = 2 * t, s1 = s0 + 1;
    int k0 = keep[s0], k1 = keep[s1];
    float g0 = gate[s0], g1 = gate[s1];
    floatx4 xv = {};
    if (!k0 || !k1) xv = ((const floatx4*)x)[i];   // block-uniform branch
    floatx4 r;
    if (k0) {
        floatx4 y0 = ((const floatx4*)ys)[((size_t)pos[s0] << 8) + c];
        r = y0 * g0;
    } else r = xv * g0;
    if (k1) {
        floatx4 y1 = ((const floatx4*)ys)[((size_t)pos[s1] << 8) + c];
        r += y1 * g1;
    } else r += xv * g1;
    ((floatx4*)out)[i] = r;
}

extern "C" void kernel_launch(void* const* d_in, const int* in_sizes, int n_in,
                              void* d_out, int out_size, void* d_ws, size_t ws_size,
                              hipStream_t stream) {
    const float* x  = (const float*)d_in[0];   // [N, D]
    const float* gw = (const float*)d_in[1];   // [D, E]
    const float* gb = (const float*)d_in[2];   // [E]
    const float* ew = (const float*)d_in[3];   // [E, D, D]
    const float* eb = (const float*)d_in[4];   // [E, D]
    float* out = (float*)d_out;                // [N, D]

    char* ws = (char*)d_ws;
    // ---- workspace layout (bytes); same offsets as round 2 ----
    int* counts      = (int*)(ws + 0);                   //    64 B
    int* slot_expert = (int*)(ws + 256);                 //  64 KB
    int* slot_keep   = (int*)(ws + 65792);               //  64 KB (temp: bpos)
    float* slot_gate = (float*)(ws + 131328);            //  64 KB
    unsigned long long* slot_key = (unsigned long long*)(ws + 196864);  // 128 KB
    unsigned long long* buckets  = (unsigned long long*)(ws + 327936);  //   2 MB
    int* elist       = (int*)(ws + 2425088);             //  64 KB
    float* gwT       = (float*)(ws + 2490624);           //  64 KB
    unsigned short* Xb = (unsigned short*)(ws + 2556160);   // 16 MB
    unsigned short* Wb = (unsigned short*)(ws + 19333376);  // 32 MB -> end 52887808
    int* slot_pos    = (int*)(ws + 52887808);            //  64 KB (ys path only)
    float* ys        = (float*)(ws + 52953344);          //  64 MB (ys path only)
    const size_t WS_NEED_YS = 52953344ull + (size_t)NEXP * CAPE * DIM * 4;  // ~114.5 MB

    const bool ys_path = (ws_size >= WS_NEED_YS);

    // 1) weight cvt + gw transpose + zero counters (fused)
    cvt_gwt_zero_kernel<<<(NEXP * DIM * DIM / 4) / 256, 256, 0, stream>>>(
        ew, Wb, gw, gwT, (int*)ws);
    // 2) gate (16 tokens/block) + fused bucket histogram (bpos in slot_keep)
    gate_kernel<<<N_TOK / 16, 256, 0, stream>>>(x, gwT, gb, slot_expert, slot_key,
                                                slot_gate, Xb, counts, buckets,
                                                slot_keep);
    // 3) keep + compact merged (rank == position, no atomics)
    keep_compact_kernel<<<NSLOT / 4, 256, 0, stream>>>(slot_expert, slot_key, counts,
                                                       buckets, slot_keep, elist,
                                                       slot_pos);

    if (ys_path) {
        moe_gemm<true><<<dim3(8, 4, 16), 512, 0, stream>>>(Xb, Wb, eb, elist, counts,
                                                           slot_gate, ys, out);
        combine_kernel<<<N_TOK, 256, 0, stream>>>(x, ys, slot_keep, slot_pos,
                                                  slot_gate, out);
    } else {
        base_kernel<<<(N_TOK * DIM / 4) / 256, 256, 0, stream>>>(x, slot_keep,
                                                                 slot_gate, out);
        moe_gemm<false><<<dim3(8, 4, 16), 512, 0, stream>>>(Xb, Wb, eb, elist, counts,
                                                            slot_gate, nullptr, out);
    }
}